// Round 4
// baseline (830.862 us; speedup 1.0000x reference)
//
#include <hip/hip_runtime.h>
#include <hip/hip_bf16.h>
#include <math.h>

// N=20000, IN_F=256, HID=128, HEADS=4, OUT_F=10, E=400000, G=64, HC=512
#define NODES   20000
#define MPAD    20096            // 157 * 128 (GEMM M padding)
#define IN_F    256
#define HID     128
#define HEADS   4
#define OUT_F   10
#define NEDGE   400000
#define NGRAPH  64
#define HC      512
#define EPRIME  (NEDGE + NODES)  // with self loops
#define XLRW    1024             // fused [xl|xr] row width (floats)

typedef __attribute__((ext_vector_type(8))) short bf16x8_t;
typedef __attribute__((ext_vector_type(4))) float f32x4_t;

// ---- packed f32 (VOP3P) helpers: CDNA full-rate v_pk_*_f32 ---------------
__device__ __forceinline__ float2 pk_add(float2 a, float2 b) {
    float2 d;
    asm("v_pk_add_f32 %0, %1, %2" : "=v"(d) : "v"(a), "v"(b));
    return d;
}
__device__ __forceinline__ float2 pk_mul(float2 a, float2 b) {
    float2 d;
    asm("v_pk_mul_f32 %0, %1, %2" : "=v"(d) : "v"(a), "v"(b));
    return d;
}
__device__ __forceinline__ float2 pk_fma(float2 a, float2 b, float2 c) {
    float2 d;
    asm("v_pk_fma_f32 %0, %1, %2, %3" : "=v"(d) : "v"(a), "v"(b), "v"(c));
    return d;
}
__device__ __forceinline__ float2 abs2(float2 s) {
    float2 r;
    r.x = __uint_as_float(__float_as_uint(s.x) & 0x7fffffffu);
    r.y = __uint_as_float(__float_as_uint(s.y) & 0x7fffffffu);
    return r;
}

// ---- split-bf16 helpers: f32 x ~= hi + lo (each bf16), err ~2^-18 ----------
__device__ __forceinline__ unsigned short bf16_rne(float f) {
    unsigned int u = __float_as_uint(f);
    u += 0x7FFFu + ((u >> 16) & 1u);
    return (unsigned short)(u >> 16);
}
__device__ __forceinline__ float bf16f(unsigned short h) {
    return __uint_as_float(((unsigned int)h) << 16);
}
__device__ __forceinline__ void split2(float f, unsigned short& hi, unsigned short& lo) {
    hi = bf16_rne(f);
    lo = bf16_rne(f - bf16f(hi));
}

#define GLOAD_LDS16(gp, lp) \
    __builtin_amdgcn_global_load_lds((const __attribute__((address_space(1))) unsigned int*)(gp), \
                                     (__attribute__((address_space(3))) unsigned int*)(lp), 16, 0, 0)

// ---------------------------------------------------------------------------
// Edge preprocessing: counting sort by dst; srcs stored pre-scaled to byte
// offsets of the fused xlr row (src * 4096).
// ---------------------------------------------------------------------------
__global__ __launch_bounds__(256) void hist_kernel(const int* __restrict__ ei,
                                                   int* __restrict__ counts) {
    int e = blockIdx.x * blockDim.x + threadIdx.x;
    if (e >= EPRIME) return;
    int dst = (e < NEDGE) ? ei[NEDGE + e] : (e - NEDGE);
    atomicAdd(&counts[dst], 1);
}

__global__ __launch_bounds__(1024) void scan_kernel(const int* __restrict__ counts,
                                                    int* __restrict__ offsets,
                                                    int* __restrict__ cursor) {
    __shared__ int wsum[16];
    __shared__ int s_carry;
    const int tid = threadIdx.x;
    const int lane = tid & 63, wid = tid >> 6;
    if (tid == 0) s_carry = 0;
    __syncthreads();
    for (int base = 0; base < NODES; base += 1024) {
        int idx = base + tid;
        int v = (idx < NODES) ? counts[idx] : 0;
        int x = v;
        #pragma unroll
        for (int d = 1; d < 64; d <<= 1) {
            int n = __shfl_up(x, d);
            if (lane >= d) x += n;
        }
        if (lane == 63) wsum[wid] = x;
        __syncthreads();
        if (wid == 0) {
            int w = (lane < 16) ? wsum[lane] : 0;
            #pragma unroll
            for (int d = 1; d < 16; d <<= 1) {
                int n = __shfl_up(w, d);
                if (lane >= d) w += n;
            }
            if (lane < 16) wsum[lane] = w;
        }
        __syncthreads();
        int carry = s_carry;
        int wpre = (wid == 0) ? 0 : wsum[wid - 1];
        int excl = carry + wpre + x - v;
        if (idx < NODES) { offsets[idx] = excl; cursor[idx] = excl; }
        __syncthreads();
        if (tid == 1023) s_carry = carry + wsum[15];
        __syncthreads();
    }
    if (tid == 0) offsets[NODES] = s_carry;
}

__global__ __launch_bounds__(256) void scatter_kernel(const int* __restrict__ ei,
                                                      int* __restrict__ cursor,
                                                      int* __restrict__ srcsb) {
    int e = blockIdx.x * blockDim.x + threadIdx.x;
    if (e >= EPRIME) return;
    int src, dst;
    if (e < NEDGE) { src = ei[e]; dst = ei[NEDGE + e]; }
    else           { src = dst = e - NEDGE; }
    int pos = atomicAdd(&cursor[dst], 1);
    srcsb[pos] = src << 12;            // byte offset: src * XLRW * 4
}

// ---------------------------------------------------------------------------
// Converters: f32 -> split-bf16 interleaved rows.
// Row layout for K logical cols: 4*K bytes; logical k = 8g+j:
//   hi short at byte g*32 + 2j ; lo short at byte g*32 + 16 + 2j
// ---------------------------------------------------------------------------
__global__ __launch_bounds__(256) void convert_x_kernel(const float* __restrict__ x,
                                                        unsigned short* __restrict__ x2) {
    int idx = blockIdx.x * 256 + threadIdx.x;     // (row, g) with g in [0, IN_F/8)
    int r = idx >> 5, g = idx & 31;
    if (r >= MPAD) return;
    __align__(16) unsigned short hv[8], lv[8];
    if (r < NODES) {
        const float* p = &x[(size_t)r * IN_F + g * 8];
        #pragma unroll
        for (int j = 0; j < 8; ++j) split2(p[j], hv[j], lv[j]);
    } else {
        #pragma unroll
        for (int j = 0; j < 8; ++j) { hv[j] = 0; lv[j] = 0; }
    }
    unsigned short* o = x2 + (size_t)r * (2 * IN_F) + g * 16;
    *reinterpret_cast<uint4*>(o)     = *reinterpret_cast<uint4*>(hv);
    *reinterpret_cast<uint4*>(o + 8) = *reinterpret_cast<uint4*>(lv);
}

// W [K][N] f32 -> WT2 [N][4*K bytes] split-interleaved (i.e. B^T, MFMA-ready)
__global__ __launch_bounds__(256) void convert_w_kernel(const float* __restrict__ W,
                                                        unsigned short* __restrict__ WT2,
                                                        int K, int N, int gshift) {
    int idx = blockIdx.x * 256 + threadIdx.x;
    int n = idx >> gshift, g = idx & ((1 << gshift) - 1);
    if (n >= N) return;
    __align__(16) unsigned short hv[8], lv[8];
    #pragma unroll
    for (int j = 0; j < 8; ++j) split2(W[(size_t)(8 * g + j) * N + n], hv[j], lv[j]);
    unsigned short* o = WT2 + (size_t)n * (2 * K) + g * 16;
    *reinterpret_cast<uint4*>(o)     = *reinterpret_cast<uint4*>(hv);
    *reinterpret_cast<uint4*>(o + 8) = *reinterpret_cast<uint4*>(lv);
}

// concat [bl|br] per layer -> biascat[3][1024]
__global__ __launch_bounds__(256) void build_bias_kernel(const float* __restrict__ bl1,
                                                         const float* __restrict__ br1,
                                                         const float* __restrict__ bl2,
                                                         const float* __restrict__ br2,
                                                         const float* __restrict__ bl3,
                                                         const float* __restrict__ br3,
                                                         float* __restrict__ out) {
    int idx = blockIdx.x * 256 + threadIdx.x;
    if (idx >= 3 * 1024) return;
    int l = idx >> 10, c = idx & 1023;
    const float* p = (l == 0) ? (c < 512 ? bl1 : br1)
                   : (l == 1) ? (c < 512 ? bl2 : br2)
                              : (c < 512 ? bl3 : br3);
    out[idx] = p[c & 511];
}

// ---------------------------------------------------------------------------
// Split-bf16 MFMA GEMM: C[M,N] = split(A) @ split(B^T)^T + bias
// 128x128 tile, 4 waves (2x2, each 64x64 = 4x4 frags of 16x16),
// BK=32 logical (128B interleaved per row), global_load_lds width 16 with
// pre-swizzled source (XOR (row&7)<<4) -> conflict-free ds_read_b128.
// 3 MFMAs per fragment pair: hi*hi + hi*lo + lo*hi.
// ---------------------------------------------------------------------------
template <int WRITE_SPLIT, int ACT>
__global__ __launch_bounds__(256) void mfma_gemm_kernel(const unsigned short* __restrict__ A2,
                                                        const unsigned short* __restrict__ B2,
                                                        const float* __restrict__ bias,
                                                        float* __restrict__ Cf,
                                                        unsigned short* __restrict__ C2,
                                                        int M, int N, int K) {
    __shared__ char lds[32768];        // [0,16K) A-tile, [16K,32K) B-tile
    const int tid = threadIdx.x;
    const int w = tid >> 6, l = tid & 63;
    const int wr = w >> 1, wc = w & 1;
    const int row0 = blockIdx.x * 128, col0 = blockIdx.y * 128;
    const size_t rowB = (size_t)K * 4;  // bytes per split row

    f32x4_t acc[4][4];
    #pragma unroll
    for (int i = 0; i < 4; ++i)
        #pragma unroll
        for (int j = 0; j < 4; ++j)
            #pragma unroll
            for (int q = 0; q < 4; ++q) acc[i][j][q] = 0.f;

    const int ssub = l >> 3;           // staging row-within-instr 0..7
    const int scol = (l & 7) * 16;     // staging byte col
    const int g16  = l >> 4;           // MFMA k-octet group
    const int fr   = l & 15;

    const char* Ab = (const char*)A2;
    const char* Bb = (const char*)B2;

    const int nsteps = K >> 5;
    for (int t = 0; t < nsteps; ++t) {
        #pragma unroll
        for (int i = 0; i < 4; ++i) {  // A: rows w*32+i*8 .. +7
            int r = w * 32 + i * 8 + ssub;
            size_t gb = (size_t)(row0 + r) * rowB + (size_t)t * 128 + (size_t)(scol ^ ((r & 7) << 4));
            GLOAD_LDS16(Ab + gb, &lds[(w * 32 + i * 8) * 128]);
        }
        #pragma unroll
        for (int i = 0; i < 4; ++i) {  // B: "rows" are output cols
            int r = w * 32 + i * 8 + ssub;
            size_t gb = (size_t)(col0 + r) * rowB + (size_t)t * 128 + (size_t)(scol ^ ((r & 7) << 4));
            GLOAD_LDS16(Bb + gb, &lds[16384 + (w * 32 + i * 8) * 128]);
        }
        asm volatile("s_waitcnt vmcnt(0)" ::: "memory");
        __syncthreads();

        bf16x8_t ah[4], al[4];
        #pragma unroll
        for (int i = 0; i < 4; ++i) {
            int r = wr * 64 + i * 16 + fr;
            int sw = (r & 7) << 4;
            ah[i] = *reinterpret_cast<const bf16x8_t*>(&lds[r * 128 + ((g16 * 32) ^ sw)]);
            al[i] = *reinterpret_cast<const bf16x8_t*>(&lds[r * 128 + ((g16 * 32 + 16) ^ sw)]);
        }
        #pragma unroll
        for (int j = 0; j < 4; ++j) {
            int r = wc * 64 + j * 16 + fr;
            int sw = (r & 7) << 4;
            bf16x8_t bh = *reinterpret_cast<const bf16x8_t*>(&lds[16384 + r * 128 + ((g16 * 32) ^ sw)]);
            bf16x8_t bl = *reinterpret_cast<const bf16x8_t*>(&lds[16384 + r * 128 + ((g16 * 32 + 16) ^ sw)]);
            #pragma unroll
            for (int i = 0; i < 4; ++i) {
                acc[i][j] = __builtin_amdgcn_mfma_f32_16x16x32_bf16(ah[i], bh, acc[i][j], 0, 0, 0);
                acc[i][j] = __builtin_amdgcn_mfma_f32_16x16x32_bf16(ah[i], bl, acc[i][j], 0, 0, 0);
                acc[i][j] = __builtin_amdgcn_mfma_f32_16x16x32_bf16(al[i], bh, acc[i][j], 0, 0, 0);
            }
        }
        __syncthreads();
    }

    // epilogue: C/D frag mapping col = l&15, row = (l>>4)*4 + reg   [m89]
    const int crb  = (l >> 4) * 4;
    const int ccol = l & 15;
    #pragma unroll
    for (int i = 0; i < 4; ++i) {
        #pragma unroll
        for (int jj = 0; jj < 4; ++jj) {
            int rg = row0 + wr * 64 + i * 16 + crb + jj;
            #pragma unroll
            for (int j = 0; j < 4; ++j) {
                int cg = col0 + wc * 64 + j * 16 + ccol;
                float v = acc[i][j][jj] + bias[cg];
                if (ACT) v = v > 0.f ? v : expm1f(v);
                if (WRITE_SPLIT) {
                    unsigned short hi, lo;
                    split2(v, hi, lo);
                    unsigned short* o = C2 + (size_t)rg * (2 * N) + (cg >> 3) * 16 + (cg & 7);
                    o[0] = hi; o[8] = lo;
                } else {
                    if (rg < M) Cf[(size_t)rg * N + cg] = v;
                }
            }
        }
    }
}

// ---------------------------------------------------------------------------
// Fused GATv2 edge kernel v3: 128 threads/node (2 waves), half-wave = head,
// lane owns 4 channels. Packed-f32 math; leaky via 0.6s+0.4|s| (abs = v_and);
// att pre-scaled by log2e folded into the 0.6/0.4 constants; 4-edge batches;
// fold-reduce over 16/8 + butterfly 4/2/1 + 4 ds_bpermute broadcasts.
// No LDS allocation, no __syncthreads.
// ---------------------------------------------------------------------------
__global__ __launch_bounds__(128) void gat_edge_kernel(const float* __restrict__ xlr,
                                                       const float* __restrict__ att,
                                                       const float* __restrict__ bias,
                                                       const int* __restrict__ offsets,
                                                       const int* __restrict__ srcsb,
                                                       unsigned short* __restrict__ h2) {
    const int node = blockIdx.x;
    if (node >= NODES) {   // zero the GEMM pad rows (ws is poisoned each call)
        ((uint4*)(h2 + (size_t)node * (2 * HC)))[threadIdx.x] = make_uint4(0u, 0u, 0u, 0u);
        return;
    }
    const int tid = threadIdx.x;
    const int head = tid >> 5;                 // 0..3 (half-wave granularity)
    const int hl   = tid & 31;                 // lane within head
    const int wl   = tid & 63;                 // lane within wave
    const int ch0  = head * HID + hl * 4;      // first of 4 channels
    const char* xlb = (const char*)xlr;
    const int laneoff = ch0 * 4;               // byte offset inside xl part

    // per-lane constants
    const float4 atv = *reinterpret_cast<const float4*>(&att[ch0]);
    const float L2E = 1.44269504f;
    const float2 a6p0 = make_float2(0.6f * L2E * atv.x, 0.6f * L2E * atv.y);
    const float2 a6p1 = make_float2(0.6f * L2E * atv.z, 0.6f * L2E * atv.w);
    const float2 a4p0 = make_float2(0.4f * L2E * atv.x, 0.4f * L2E * atv.y);
    const float2 a4p1 = make_float2(0.4f * L2E * atv.z, 0.4f * L2E * atv.w);
    const float4 xrv = *reinterpret_cast<const float4*>(&xlr[(size_t)node * XLRW + 512 + ch0]);
    const float2 xrp0 = make_float2(xrv.x, xrv.y);
    const float2 xrp1 = make_float2(xrv.z, xrv.w);

    // bpermute byte-indices for the 4 edge-sum broadcast slots
    const int ibase = ((wl & 32) + (wl & 7)) << 2;
    const int idx0 = ibase, idx1 = ibase + (8 << 2);
    const int idx2 = ibase + (16 << 2), idx3 = ibase + (24 << 2);

    const int beg = offsets[node], end = offsets[node + 1];
    const bool b4 = (hl & 16) != 0, b3 = (hl & 8) != 0;

    float m = -INFINITY, denom = 0.f;
    float a0 = 0.f, a1 = 0.f, a2 = 0.f, a3 = 0.f;

    for (int e0 = beg; e0 < end; e0 += 4) {
        const int nb = min(4, end - e0);       // >=1 (self loop)
        int sb[4]; float4 xv[4]; float p[4];
        #pragma unroll
        for (int q = 0; q < 4; ++q) sb[q] = srcsb[e0 + ((q < nb) ? q : nb - 1)];
        #pragma unroll
        for (int q = 0; q < 4; ++q)
            xv[q] = *reinterpret_cast<const float4*>(xlb + (size_t)(unsigned)sb[q] + laneoff);
        #pragma unroll
        for (int q = 0; q < 4; ++q) {
            float2 s0 = pk_add(make_float2(xv[q].x, xv[q].y), xrp0);
            float2 s1 = pk_add(make_float2(xv[q].z, xv[q].w), xrp1);
            float2 pp = pk_mul(a6p0, s0);
            pp = pk_fma(a4p0, abs2(s0), pp);
            pp = pk_fma(a6p1, s1, pp);
            pp = pk_fma(a4p1, abs2(s1), pp);
            p[q] = pp.x + pp.y;
        }
        // fold-reduce within the 32-lane half: 4 edge sums
        float s0 = b4 ? p[0] : p[2];
        float u0 = (b4 ? p[2] : p[0]) + __shfl_xor(s0, 16);
        float s1 = b4 ? p[1] : p[3];
        float u1 = (b4 ? p[3] : p[1]) + __shfl_xor(s1, 16);
        float s2 = b3 ? u0 : u1;
        float t  = (b3 ? u1 : u0) + __shfl_xor(s2, 8);
        t += __shfl_xor(t, 4);
        t += __shfl_xor(t, 2);
        t += __shfl_xor(t, 1);
        // edge q's full sum sits in 8-lane group (b4=q>>1, b3=q&1)
        const int ti = __float_as_int(t);
        const float pe0 = __int_as_float(__builtin_amdgcn_ds_bpermute(idx0, ti));
        const float pe1 = __int_as_float(__builtin_amdgcn_ds_bpermute(idx1, ti));
        const float pe2 = __int_as_float(__builtin_amdgcn_ds_bpermute(idx2, ti));
        const float pe3 = __int_as_float(__builtin_amdgcn_ds_bpermute(idx3, ti));

        const float m4 = fmaxf(fmaxf(pe0, pe1), fmaxf(pe2, pe3));
        if (m4 > m) {
            float sc = exp2f(m - m4);
            denom *= sc; a0 *= sc; a1 *= sc; a2 *= sc; a3 *= sc;
            m = m4;
        }
        {
            float w0 = exp2f(pe0 - m);
            denom += w0;
            a0 = fmaf(w0, xv[0].x, a0); a1 = fmaf(w0, xv[0].y, a1);
            a2 = fmaf(w0, xv[0].z, a2); a3 = fmaf(w0, xv[0].w, a3);
        }
        if (nb > 1) {
            float w1 = exp2f(pe1 - m);
            denom += w1;
            a0 = fmaf(w1, xv[1].x, a0); a1 = fmaf(w1, xv[1].y, a1);
            a2 = fmaf(w1, xv[1].z, a2); a3 = fmaf(w1, xv[1].w, a3);
        }
        if (nb > 2) {
            float w2 = exp2f(pe2 - m);
            denom += w2;
            a0 = fmaf(w2, xv[2].x, a0); a1 = fmaf(w2, xv[2].y, a1);
            a2 = fmaf(w2, xv[2].z, a2); a3 = fmaf(w2, xv[2].w, a3);
        }
        if (nb > 3) {
            float w3 = exp2f(pe3 - m);
            denom += w3;
            a0 = fmaf(w3, xv[3].x, a0); a1 = fmaf(w3, xv[3].y, a1);
            a2 = fmaf(w3, xv[3].z, a2); a3 = fmaf(w3, xv[3].w, a3);
        }
    }

    const float inv = 1.f / denom;
    const float4 bv = *reinterpret_cast<const float4*>(&bias[ch0]);
    float o0 = a0 * inv + bv.x, o1 = a1 * inv + bv.y;
    float o2 = a2 * inv + bv.z, o3 = a3 * inv + bv.w;
    o0 = o0 > 0.f ? o0 : expm1f(o0);
    o1 = o1 > 0.f ? o1 : expm1f(o1);
    o2 = o2 > 0.f ? o2 : expm1f(o2);
    o3 = o3 > 0.f ? o3 : expm1f(o3);
    __align__(8) unsigned short hv[4], lv[4];
    split2(o0, hv[0], lv[0]); split2(o1, hv[1], lv[1]);
    split2(o2, hv[2], lv[2]); split2(o3, hv[3], lv[3]);
    // split layout: hi at byte g*32 + 2j, lo at +16 ; our 4 ch are j0=ch0&7 in {0,4}
    unsigned short* o = h2 + (size_t)node * (2 * HC) + ((ch0 >> 3) * 16) + (ch0 & 7);
    *reinterpret_cast<uint2*>(o)     = *reinterpret_cast<uint2*>(hv);
    *reinterpret_cast<uint2*>(o + 8) = *reinterpret_cast<uint2*>(lv);
}

// ---------------------------------------------------------------------------
// Pool stage 1: per (graph, quarter) partial sums (deterministic, no atomics)
// ---------------------------------------------------------------------------
__global__ __launch_bounds__(256) void pool_part_kernel(const unsigned short* __restrict__ h2,
                                                        const int* __restrict__ batch,
                                                        float* __restrict__ partial) {
    const int g = blockIdx.x, part = blockIdx.y;
    int lo = 0, hi = NODES;
    while (lo < hi) { int mid = (lo + hi) >> 1; if (batch[mid] < g) lo = mid + 1; else hi = mid; }
    const int s = lo;
    lo = s; hi = NODES;
    while (lo < hi) { int mid = (lo + hi) >> 1; if (batch[mid] < g + 1) lo = mid + 1; else hi = mid; }
    const int e = lo, cnt = e - s;
    const int ps = s + (cnt * part) / 4;
    const int pe = s + (cnt * (part + 1)) / 4;

    const int c0 = threadIdx.x * 2;
    const int boff = ((c0 >> 3) * 16) + (c0 & 7);
    float s0 = 0.f, s1 = 0.f;
    for (int r = ps; r < pe; ++r) {
        const unsigned short* p = h2 + (size_t)r * (2 * HC) + boff;
        s0 += bf16f(p[0]) + bf16f(p[8]);
        s1 += bf16f(p[1]) + bf16f(p[9]);
    }
    float* o = partial + ((size_t)(g * 4 + part)) * HC;
    o[c0] = s0; o[c0 + 1] = s1;
}

// ---------------------------------------------------------------------------
// Pool stage 2 + classifier
// ---------------------------------------------------------------------------
__global__ __launch_bounds__(256) void cls_kernel(const float* __restrict__ partial,
                                                  const int* __restrict__ batch,
                                                  const float* __restrict__ W,
                                                  const float* __restrict__ cb,
                                                  float* __restrict__ outp) {
    const int g = blockIdx.x;
    __shared__ float pooled[HC];
    int lo = 0, hi = NODES;
    while (lo < hi) { int mid = (lo + hi) >> 1; if (batch[mid] < g) lo = mid + 1; else hi = mid; }
    const int s = lo;
    lo = s; hi = NODES;
    while (lo < hi) { int mid = (lo + hi) >> 1; if (batch[mid] < g + 1) lo = mid + 1; else hi = mid; }
    const int cnt = lo - s;

    const int c0 = threadIdx.x * 2;
    float s0 = 0.f, s1 = 0.f;
    #pragma unroll
    for (int part = 0; part < 4; ++part) {
        const float* p = partial + ((size_t)(g * 4 + part)) * HC;
        s0 += p[c0]; s1 += p[c0 + 1];
    }
    const float invc = cnt > 0 ? 1.f / (float)cnt : 0.f;
    pooled[c0] = s0 * invc; pooled[c0 + 1] = s1 * invc;
    __syncthreads();

    const int lane = threadIdx.x & 63, wid = threadIdx.x >> 6;
    for (int o = wid; o < OUT_F; o += 4) {
        float p = 0.f;
        for (int c = lane; c < HC; c += 64) p += pooled[c] * W[c * OUT_F + o];
        #pragma unroll
        for (int off2 = 32; off2; off2 >>= 1) p += __shfl_xor(p, off2);
        if (lane == 0) outp[g * OUT_F + o] = p + cb[o];
    }
}

// ---------------------------------------------------------------------------
// Host-side launch
// ---------------------------------------------------------------------------
extern "C" void kernel_launch(void* const* d_in, const int* in_sizes, int n_in,
                              void* d_out, int out_size, void* d_ws, size_t ws_size,
                              hipStream_t stream) {
    const float* x      = (const float*)d_in[0];
    const int*   ei     = (const int*)d_in[1];
    const int*   batch  = (const int*)d_in[2];
    const float* pre_W  = (const float*)d_in[3];
    const float* pre_b  = (const float*)d_in[4];
    const float* cls_W  = (const float*)d_in[5];
    const float* cls_b  = (const float*)d_in[6];
    const float* Wl[3]; const float* bl[3]; const float* Wr[3];
    const float* br[3]; const float* attw[3]; const float* bw[3];
    for (int l = 0; l < 3; ++l) {
        Wl[l]   = (const float*)d_in[7 + 6 * l + 0];
        bl[l]   = (const float*)d_in[7 + 6 * l + 1];
        Wr[l]   = (const float*)d_in[7 + 6 * l + 2];
        br[l]   = (const float*)d_in[7 + 6 * l + 3];
        attw[l] = (const float*)d_in[7 + 6 * l + 4];
        bw[l]   = (const float*)d_in[7 + 6 * l + 5];
    }
    float* outp = (float*)d_out;

    // ---- workspace carve (~128 MB, lifetime-aliased) ----
    char* ws = (char*)d_ws;
    size_t off = 0;
    auto alloc = [&](size_t b) { char* p = ws + off; off += (b + 255) & ~(size_t)255; return p; };
    float* xlr = (float*)alloc((size_t)MPAD * XLRW * 4);                // 82.3 MB
    unsigned short* h2 = (unsigned short*)alloc((size_t)MPAD * 2 * HC * 2); // 41.2 MB
    unsigned short* WT2f = (unsigned short*)alloc((size_t)1024 * 2 * HC * 2); // 2.1 MB (K<=512)
    unsigned short* preWT2 = (unsigned short*)alloc((size_t)HID * 2 * IN_F * 2); // 131 KB
    float* biascat = (float*)alloc(3 * 1024 * 4);
    int* counts  = (int*)alloc(NODES * 4);
    int* offsets = (int*)alloc((NODES + 1) * 4);
    int* cursor  = (int*)alloc(NODES * 4);
    int* srcsb   = (int*)alloc((size_t)EPRIME * 4);
    // aliases (disjoint lifetimes):
    unsigned short* x2 = (unsigned short*)xlr;   // dead before xlr written (L1 GEMM)
    float* partial = xlr;                        // pool runs after xlr is dead

    // ---- edge sort ----
    hipMemsetAsync(counts, 0, NODES * 4, stream);
    hist_kernel<<<(EPRIME + 255) / 256, 256, 0, stream>>>(ei, counts);
    scan_kernel<<<1, 1024, 0, stream>>>(counts, offsets, cursor);
    scatter_kernel<<<(EPRIME + 255) / 256, 256, 0, stream>>>(ei, cursor, srcsb);

    // ---- conversions ----
    convert_x_kernel<<<(MPAD * (IN_F / 8) + 255) / 256, 256, 0, stream>>>(x, x2);
    convert_w_kernel<<<(HID * (IN_F / 8) + 255) / 256, 256, 0, stream>>>(pre_W, preWT2, IN_F, HID, 5);
    build_bias_kernel<<<12, 256, 0, stream>>>(bl[0], br[0], bl[1], br[1], bl[2], br[2], biascat);
    // layer 0 fused weights: rows 0..511 = Wl, rows 512..1023 = Wr (row stride 2*K shorts)
    convert_w_kernel<<<(HC * (HID / 8) + 255) / 256, 256, 0, stream>>>(Wl[0], WT2f, HID, HC, 4);
    convert_w_kernel<<<(HC * (HID / 8) + 255) / 256, 256, 0, stream>>>(Wr[0], WT2f + (size_t)512 * 2 * HID, HID, HC, 4);

    // ---- pre layer: h = elu(x @ pre_W + pre_b), split-written ----
    mfma_gemm_kernel<1, 1><<<dim3(157, 1), 256, 0, stream>>>(x2, preWT2, pre_b,
                                                             nullptr, h2, NODES, HID, IN_F);

    // ---- layer 1 (fused Wl|Wr GEMM, N=1024) ----
    mfma_gemm_kernel<0, 0><<<dim3(157, 8), 256, 0, stream>>>(h2, WT2f, biascat, xlr, nullptr, NODES, 1024, HID);
    convert_w_kernel<<<(HC * (HC / 8) + 255) / 256, 256, 0, stream>>>(Wl[1], WT2f, HC, HC, 6);
    convert_w_kernel<<<(HC * (HC / 8) + 255) / 256, 256, 0, stream>>>(Wr[1], WT2f + (size_t)512 * 2 * HC, HC, HC, 6);
    gat_edge_kernel<<<MPAD, 128, 0, stream>>>(xlr, attw[0], bw[0], offsets, srcsb, h2);

    // ---- layer 2 ----
    mfma_gemm_kernel<0, 0><<<dim3(157, 8), 256, 0, stream>>>(h2, WT2f, biascat + 1024, xlr, nullptr, NODES, 1024, HC);
    convert_w_kernel<<<(HC * (HC / 8) + 255) / 256, 256, 0, stream>>>(Wl[2], WT2f, HC, HC, 6);
    convert_w_kernel<<<(HC * (HC / 8) + 255) / 256, 256, 0, stream>>>(Wr[2], WT2f + (size_t)512 * 2 * HC, HC, HC, 6);
    gat_edge_kernel<<<MPAD, 128, 0, stream>>>(xlr, attw[1], bw[1], offsets, srcsb, h2);

    // ---- layer 3 ----
    mfma_gemm_kernel<0, 0><<<dim3(157, 8), 256, 0, stream>>>(h2, WT2f, biascat + 2048, xlr, nullptr, NODES, 1024, HC);
    gat_edge_kernel<<<MPAD, 128, 0, stream>>>(xlr, attw[2], bw[2], offsets, srcsb, h2);

    // ---- pool + classifier ----
    pool_part_kernel<<<dim3(NGRAPH, 4), 256, 0, stream>>>(h2, batch, partial);
    cls_kernel<<<NGRAPH, 256, 0, stream>>>(partial, batch, cls_W, cls_b, outp);
}

// Round 6
// 821.837 us; speedup vs baseline: 1.0110x; 1.0110x over previous
//
#include <hip/hip_runtime.h>
#include <hip/hip_bf16.h>
#include <math.h>

// N=20000, IN_F=256, HID=128, HEADS=4, OUT_F=10, E=400000, G=64, HC=512
#define NODES   20000
#define MPAD    20096            // 157 * 128 (GEMM M padding)
#define IN_F    256
#define HID     128
#define HEADS   4
#define OUT_F   10
#define NEDGE   400000
#define NGRAPH  64
#define HC      512
#define EPRIME  (NEDGE + NODES)  // with self loops
#define XLRW    1024             // fused [xl|xr] row width (floats)

typedef __attribute__((ext_vector_type(8))) short bf16x8_t;
typedef __attribute__((ext_vector_type(4))) float f32x4_t;

// ---- packed f32 (VOP3P) helpers: CDNA full-rate v_pk_*_f32 ---------------
__device__ __forceinline__ float2 pk_add(float2 a, float2 b) {
    float2 d;
    asm("v_pk_add_f32 %0, %1, %2" : "=v"(d) : "v"(a), "v"(b));
    return d;
}
__device__ __forceinline__ float2 pk_mul(float2 a, float2 b) {
    float2 d;
    asm("v_pk_mul_f32 %0, %1, %2" : "=v"(d) : "v"(a), "v"(b));
    return d;
}
__device__ __forceinline__ float2 pk_fma(float2 a, float2 b, float2 c) {
    float2 d;
    asm("v_pk_fma_f32 %0, %1, %2, %3" : "=v"(d) : "v"(a), "v"(b), "v"(c));
    return d;
}
__device__ __forceinline__ float2 abs2(float2 s) {
    float2 r;
    r.x = __uint_as_float(__float_as_uint(s.x) & 0x7fffffffu);
    r.y = __uint_as_float(__float_as_uint(s.y) & 0x7fffffffu);
    return r;
}

// ---- split-bf16 helpers: f32 x ~= hi + lo (each bf16), err ~2^-18 ----------
__device__ __forceinline__ unsigned short bf16_rne(float f) {
    unsigned int u = __float_as_uint(f);
    u += 0x7FFFu + ((u >> 16) & 1u);
    return (unsigned short)(u >> 16);
}
__device__ __forceinline__ float bf16f(unsigned short h) {
    return __uint_as_float(((unsigned int)h) << 16);
}
__device__ __forceinline__ void split2(float f, unsigned short& hi, unsigned short& lo) {
    hi = bf16_rne(f);
    lo = bf16_rne(f - bf16f(hi));
}

#define GLOAD_LDS16(gp, lp) \
    __builtin_amdgcn_global_load_lds((const __attribute__((address_space(1))) unsigned int*)(gp), \
                                     (__attribute__((address_space(3))) unsigned int*)(lp), 16, 0, 0)

// ---------------------------------------------------------------------------
// Edge preprocessing: counting sort by dst; srcs stored pre-scaled to byte
// offsets of the fused xlr row (src * 4096).
// ---------------------------------------------------------------------------
__global__ __launch_bounds__(256) void hist_kernel(const int* __restrict__ ei,
                                                   int* __restrict__ counts) {
    int e = blockIdx.x * blockDim.x + threadIdx.x;
    if (e >= EPRIME) return;
    int dst = (e < NEDGE) ? ei[NEDGE + e] : (e - NEDGE);
    atomicAdd(&counts[dst], 1);
}

__global__ __launch_bounds__(1024) void scan_kernel(const int* __restrict__ counts,
                                                    int* __restrict__ offsets,
                                                    int* __restrict__ cursor) {
    __shared__ int wsum[16];
    __shared__ int s_carry;
    const int tid = threadIdx.x;
    const int lane = tid & 63, wid = tid >> 6;
    if (tid == 0) s_carry = 0;
    __syncthreads();
    for (int base = 0; base < NODES; base += 1024) {
        int idx = base + tid;
        int v = (idx < NODES) ? counts[idx] : 0;
        int x = v;
        #pragma unroll
        for (int d = 1; d < 64; d <<= 1) {
            int n = __shfl_up(x, d);
            if (lane >= d) x += n;
        }
        if (lane == 63) wsum[wid] = x;
        __syncthreads();
        if (wid == 0) {
            int w = (lane < 16) ? wsum[lane] : 0;
            #pragma unroll
            for (int d = 1; d < 16; d <<= 1) {
                int n = __shfl_up(w, d);
                if (lane >= d) w += n;
            }
            if (lane < 16) wsum[lane] = w;
        }
        __syncthreads();
        int carry = s_carry;
        int wpre = (wid == 0) ? 0 : wsum[wid - 1];
        int excl = carry + wpre + x - v;
        if (idx < NODES) { offsets[idx] = excl; cursor[idx] = excl; }
        __syncthreads();
        if (tid == 1023) s_carry = carry + wsum[15];
        __syncthreads();
    }
    if (tid == 0) offsets[NODES] = s_carry;
}

__global__ __launch_bounds__(256) void scatter_kernel(const int* __restrict__ ei,
                                                      int* __restrict__ cursor,
                                                      int* __restrict__ srcsb) {
    int e = blockIdx.x * blockDim.x + threadIdx.x;
    if (e >= EPRIME) return;
    int src, dst;
    if (e < NEDGE) { src = ei[e]; dst = ei[NEDGE + e]; }
    else           { src = dst = e - NEDGE; }
    int pos = atomicAdd(&cursor[dst], 1);
    srcsb[pos] = src << 12;            // byte offset: src * XLRW * 4
}

// ---------------------------------------------------------------------------
// Converters: f32 -> split-bf16 interleaved rows.
// Row layout for K logical cols: 4*K bytes; logical k = 8g+j:
//   hi short at byte g*32 + 2j ; lo short at byte g*32 + 16 + 2j
// ---------------------------------------------------------------------------
__global__ __launch_bounds__(256) void convert_x_kernel(const float* __restrict__ x,
                                                        unsigned short* __restrict__ x2) {
    int idx = blockIdx.x * 256 + threadIdx.x;     // (row, g) with g in [0, IN_F/8)
    int r = idx >> 5, g = idx & 31;
    if (r >= MPAD) return;
    __align__(16) unsigned short hv[8], lv[8];
    if (r < NODES) {
        const float* p = &x[(size_t)r * IN_F + g * 8];
        #pragma unroll
        for (int j = 0; j < 8; ++j) split2(p[j], hv[j], lv[j]);
    } else {
        #pragma unroll
        for (int j = 0; j < 8; ++j) { hv[j] = 0; lv[j] = 0; }
    }
    unsigned short* o = x2 + (size_t)r * (2 * IN_F) + g * 16;
    *reinterpret_cast<uint4*>(o)     = *reinterpret_cast<uint4*>(hv);
    *reinterpret_cast<uint4*>(o + 8) = *reinterpret_cast<uint4*>(lv);
}

// W [K][N] f32 -> WT2 [N][4*K bytes] split-interleaved (i.e. B^T, MFMA-ready)
__global__ __launch_bounds__(256) void convert_w_kernel(const float* __restrict__ W,
                                                        unsigned short* __restrict__ WT2,
                                                        int K, int N, int gshift) {
    int idx = blockIdx.x * 256 + threadIdx.x;
    int n = idx >> gshift, g = idx & ((1 << gshift) - 1);
    if (n >= N) return;
    __align__(16) unsigned short hv[8], lv[8];
    #pragma unroll
    for (int j = 0; j < 8; ++j) split2(W[(size_t)(8 * g + j) * N + n], hv[j], lv[j]);
    unsigned short* o = WT2 + (size_t)n * (2 * K) + g * 16;
    *reinterpret_cast<uint4*>(o)     = *reinterpret_cast<uint4*>(hv);
    *reinterpret_cast<uint4*>(o + 8) = *reinterpret_cast<uint4*>(lv);
}

// concat [bl|br] per layer -> biascat[3][1024]
__global__ __launch_bounds__(256) void build_bias_kernel(const float* __restrict__ bl1,
                                                         const float* __restrict__ br1,
                                                         const float* __restrict__ bl2,
                                                         const float* __restrict__ br2,
                                                         const float* __restrict__ bl3,
                                                         const float* __restrict__ br3,
                                                         float* __restrict__ out) {
    int idx = blockIdx.x * 256 + threadIdx.x;
    if (idx >= 3 * 1024) return;
    int l = idx >> 10, c = idx & 1023;
    const float* p = (l == 0) ? (c < 512 ? bl1 : br1)
                   : (l == 1) ? (c < 512 ? bl2 : br2)
                              : (c < 512 ? bl3 : br3);
    out[idx] = p[c & 511];
}

// ---------------------------------------------------------------------------
// Split-bf16 MFMA GEMM: C[M,N] = split(A) @ split(B^T)^T + bias
// 128x128 tile, 4 waves (2x2, each 64x64 = 4x4 frags of 16x16),
// BK=32 logical (128B interleaved per row), global_load_lds width 16 with
// pre-swizzled source (XOR (row&7)<<4) -> conflict-free ds_read_b128.
// 3 MFMAs per fragment pair: hi*hi + hi*lo + lo*hi.
// ---------------------------------------------------------------------------
template <int WRITE_SPLIT, int ACT>
__global__ __launch_bounds__(256) void mfma_gemm_kernel(const unsigned short* __restrict__ A2,
                                                        const unsigned short* __restrict__ B2,
                                                        const float* __restrict__ bias,
                                                        float* __restrict__ Cf,
                                                        unsigned short* __restrict__ C2,
                                                        int M, int N, int K) {
    __shared__ char lds[32768];        // [0,16K) A-tile, [16K,32K) B-tile
    const int tid = threadIdx.x;
    const int w = tid >> 6, l = tid & 63;
    const int wr = w >> 1, wc = w & 1;
    const int row0 = blockIdx.x * 128, col0 = blockIdx.y * 128;
    const size_t rowB = (size_t)K * 4;  // bytes per split row

    f32x4_t acc[4][4];
    #pragma unroll
    for (int i = 0; i < 4; ++i)
        #pragma unroll
        for (int j = 0; j < 4; ++j)
            #pragma unroll
            for (int q = 0; q < 4; ++q) acc[i][j][q] = 0.f;

    const int ssub = l >> 3;           // staging row-within-instr 0..7
    const int scol = (l & 7) * 16;     // staging byte col
    const int g16  = l >> 4;           // MFMA k-octet group
    const int fr   = l & 15;

    const char* Ab = (const char*)A2;
    const char* Bb = (const char*)B2;

    const int nsteps = K >> 5;
    for (int t = 0; t < nsteps; ++t) {
        #pragma unroll
        for (int i = 0; i < 4; ++i) {  // A: rows w*32+i*8 .. +7
            int r = w * 32 + i * 8 + ssub;
            size_t gb = (size_t)(row0 + r) * rowB + (size_t)t * 128 + (size_t)(scol ^ ((r & 7) << 4));
            GLOAD_LDS16(Ab + gb, &lds[(w * 32 + i * 8) * 128]);
        }
        #pragma unroll
        for (int i = 0; i < 4; ++i) {  // B: "rows" are output cols
            int r = w * 32 + i * 8 + ssub;
            size_t gb = (size_t)(col0 + r) * rowB + (size_t)t * 128 + (size_t)(scol ^ ((r & 7) << 4));
            GLOAD_LDS16(Bb + gb, &lds[16384 + (w * 32 + i * 8) * 128]);
        }
        asm volatile("s_waitcnt vmcnt(0)" ::: "memory");
        __syncthreads();

        bf16x8_t ah[4], al[4];
        #pragma unroll
        for (int i = 0; i < 4; ++i) {
            int r = wr * 64 + i * 16 + fr;
            int sw = (r & 7) << 4;
            ah[i] = *reinterpret_cast<const bf16x8_t*>(&lds[r * 128 + ((g16 * 32) ^ sw)]);
            al[i] = *reinterpret_cast<const bf16x8_t*>(&lds[r * 128 + ((g16 * 32 + 16) ^ sw)]);
        }
        #pragma unroll
        for (int j = 0; j < 4; ++j) {
            int r = wc * 64 + j * 16 + fr;
            int sw = (r & 7) << 4;
            bf16x8_t bh = *reinterpret_cast<const bf16x8_t*>(&lds[16384 + r * 128 + ((g16 * 32) ^ sw)]);
            bf16x8_t bl = *reinterpret_cast<const bf16x8_t*>(&lds[16384 + r * 128 + ((g16 * 32 + 16) ^ sw)]);
            #pragma unroll
            for (int i = 0; i < 4; ++i) {
                acc[i][j] = __builtin_amdgcn_mfma_f32_16x16x32_bf16(ah[i], bh, acc[i][j], 0, 0, 0);
                acc[i][j] = __builtin_amdgcn_mfma_f32_16x16x32_bf16(ah[i], bl, acc[i][j], 0, 0, 0);
                acc[i][j] = __builtin_amdgcn_mfma_f32_16x16x32_bf16(al[i], bh, acc[i][j], 0, 0, 0);
            }
        }
        __syncthreads();
    }

    // epilogue: C/D frag mapping col = l&15, row = (l>>4)*4 + reg   [m89]
    const int crb  = (l >> 4) * 4;
    const int ccol = l & 15;
    #pragma unroll
    for (int i = 0; i < 4; ++i) {
        #pragma unroll
        for (int jj = 0; jj < 4; ++jj) {
            int rg = row0 + wr * 64 + i * 16 + crb + jj;
            #pragma unroll
            for (int j = 0; j < 4; ++j) {
                int cg = col0 + wc * 64 + j * 16 + ccol;
                float v = acc[i][j][jj] + bias[cg];
                if (ACT) v = v > 0.f ? v : expm1f(v);
                if (WRITE_SPLIT) {
                    unsigned short hi, lo;
                    split2(v, hi, lo);
                    unsigned short* o = C2 + (size_t)rg * (2 * N) + (cg >> 3) * 16 + (cg & 7);
                    o[0] = hi; o[8] = lo;
                } else {
                    if (rg < M) Cf[(size_t)rg * N + cg] = v;
                }
            }
        }
    }
}

// ---------------------------------------------------------------------------
// Fused GATv2 edge kernel v5: 256 threads = 2 nodes/block (4 waves).
// Within a node's 128 threads: half-wave = head, lane owns 4 channels.
// 8-edge batches (8 float4 gathers in flight) + double-buffered prefetch of
// the next batch. Packed-f32 math, leaky via 0.6s+0.4|s|, exp2 domain.
// Reduce: fold 8->4 (xor16), 4->2 (xor8), 2->1 (xor4), butterfly 2/1,
// then 8 ds_bpermute broadcasts (edge e lives on lanes 4e..4e+3).
// ---------------------------------------------------------------------------
__global__ __launch_bounds__(256) void gat_edge_kernel(const float* __restrict__ xlr,
                                                       const float* __restrict__ att,
                                                       const float* __restrict__ bias,
                                                       const int* __restrict__ offsets,
                                                       const int* __restrict__ srcsb,
                                                       unsigned short* __restrict__ h2) {
    const int tid = threadIdx.x;
    const int grp = tid >> 7;                  // node sub-group 0/1
    const int node = blockIdx.x * 2 + grp;
    const int t = tid & 127;
    if (node >= NODES) {   // zero the GEMM pad rows (ws is poisoned each call)
        ((uint4*)(h2 + (size_t)node * (2 * HC)))[t] = make_uint4(0u, 0u, 0u, 0u);
        return;
    }
    const int head = t >> 5;                   // 0..3 (half-wave granularity)
    const int hl   = t & 31;                   // lane within head
    const int wl   = tid & 63;                 // lane within wave
    const int ch0  = head * HID + hl * 4;      // first of 4 channels
    const char* xlb = (const char*)xlr;
    const int laneoff = ch0 * 4;               // byte offset inside xl part

    // per-lane constants
    const float4 atv = *reinterpret_cast<const float4*>(&att[ch0]);
    const float L2E = 1.44269504f;
    const float2 a6p0 = make_float2(0.6f * L2E * atv.x, 0.6f * L2E * atv.y);
    const float2 a6p1 = make_float2(0.6f * L2E * atv.z, 0.6f * L2E * atv.w);
    const float2 a4p0 = make_float2(0.4f * L2E * atv.x, 0.4f * L2E * atv.y);
    const float2 a4p1 = make_float2(0.4f * L2E * atv.z, 0.4f * L2E * atv.w);
    const float4 xrv = *reinterpret_cast<const float4*>(&xlr[(size_t)node * XLRW + 512 + ch0]);
    const float2 xrp0 = make_float2(xrv.x, xrv.y);
    const float2 xrp1 = make_float2(xrv.z, xrv.w);

    // bpermute byte-indices: edge e's sum lives on lanes (wl&32) + 4e + 0..3
    const int ibase = ((wl & 32) | (wl & 3)) << 2;

    const int beg = offsets[node], end = offsets[node + 1];
    const bool b4 = (hl & 16) != 0, b3 = (hl & 8) != 0, b2 = (hl & 4) != 0;

    float m = -INFINITY, denom = 0.f;
    float a0 = 0.f, a1 = 0.f, a2 = 0.f, a3 = 0.f;

    int e0 = beg;
    int nb = min(8, end - beg);                // >=1 (self loop)
    int sb[8]; float4 xv[8];
    #pragma unroll
    for (int q = 0; q < 8; ++q) sb[q] = srcsb[e0 + ((q < nb) ? q : nb - 1)];
    #pragma unroll
    for (int q = 0; q < 8; ++q)
        xv[q] = *reinterpret_cast<const float4*>(xlb + (size_t)(unsigned)sb[q] + laneoff);

    while (true) {
        // ---- prefetch next batch (overlaps with compute below) ----
        const int e1 = e0 + 8;
        const bool more = e1 < end;
        int nbn = 0;
        int sbn[8]; float4 xvn[8];
        if (more) {
            nbn = min(8, end - e1);
            #pragma unroll
            for (int q = 0; q < 8; ++q) sbn[q] = srcsb[e1 + ((q < nbn) ? q : nbn - 1)];
            #pragma unroll
            for (int q = 0; q < 8; ++q)
                xvn[q] = *reinterpret_cast<const float4*>(xlb + (size_t)(unsigned)sbn[q] + laneoff);
        }

        // ---- per-edge partial logits (4 channels/lane, packed math) ----
        float p[8];
        #pragma unroll
        for (int q = 0; q < 8; ++q) {
            float2 s0 = pk_add(make_float2(xv[q].x, xv[q].y), xrp0);
            float2 s1 = pk_add(make_float2(xv[q].z, xv[q].w), xrp1);
            float2 pp = pk_mul(a6p0, s0);
            pp = pk_fma(a4p0, abs2(s0), pp);
            pp = pk_fma(a6p1, s1, pp);
            pp = pk_fma(a4p1, abs2(s1), pp);
            p[q] = pp.x + pp.y;
        }
        // ---- fold-reduce: 8 edge-sums over the 32-lane half ----
        float u[4];
        #pragma unroll
        for (int q = 0; q < 4; ++q) {
            float s = b4 ? p[q] : p[q + 4];
            u[q] = (b4 ? p[q + 4] : p[q]) + __shfl_xor(s, 16);
        }
        float v0, v1;
        { float s = b3 ? u[0] : u[2]; v0 = (b3 ? u[2] : u[0]) + __shfl_xor(s, 8); }
        { float s = b3 ? u[1] : u[3]; v1 = (b3 ? u[3] : u[1]) + __shfl_xor(s, 8); }
        float tt;
        { float s = b2 ? v0 : v1; tt = (b2 ? v1 : v0) + __shfl_xor(s, 4); }
        tt += __shfl_xor(tt, 2);
        tt += __shfl_xor(tt, 1);
        // edge e = (lane>>2)&7 holds the full sum on lanes 4e..4e+3
        const int ti = __float_as_int(tt);
        float pe[8];
        #pragma unroll
        for (int q = 0; q < 8; ++q)
            pe[q] = __int_as_float(__builtin_amdgcn_ds_bpermute(ibase + (q << 4), ti));

        const float m8 = fmaxf(fmaxf(fmaxf(pe[0], pe[1]), fmaxf(pe[2], pe[3])),
                               fmaxf(fmaxf(pe[4], pe[5]), fmaxf(pe[6], pe[7])));
        if (m8 > m) {
            float sc = exp2f(m - m8);
            denom *= sc; a0 *= sc; a1 *= sc; a2 *= sc; a3 *= sc;
            m = m8;
        }
        #pragma unroll
        for (int q = 0; q < 8; ++q) {
            if (q >= nb) break;                 // wave-uniform
            float wq = exp2f(pe[q] - m);
            denom += wq;
            a0 = fmaf(wq, xv[q].x, a0); a1 = fmaf(wq, xv[q].y, a1);
            a2 = fmaf(wq, xv[q].z, a2); a3 = fmaf(wq, xv[q].w, a3);
        }

        if (!more) break;
        #pragma unroll
        for (int q = 0; q < 8; ++q) { sb[q] = sbn[q]; xv[q] = xvn[q]; }
        nb = nbn; e0 = e1;
    }

    const float inv = 1.f / denom;
    const float4 bv = *reinterpret_cast<const float4*>(&bias[ch0]);
    float o0 = a0 * inv + bv.x, o1 = a1 * inv + bv.y;
    float o2 = a2 * inv + bv.z, o3 = a3 * inv + bv.w;
    o0 = o0 > 0.f ? o0 : expm1f(o0);
    o1 = o1 > 0.f ? o1 : expm1f(o1);
    o2 = o2 > 0.f ? o2 : expm1f(o2);
    o3 = o3 > 0.f ? o3 : expm1f(o3);
    __align__(8) unsigned short hv[4], lv[4];
    split2(o0, hv[0], lv[0]); split2(o1, hv[1], lv[1]);
    split2(o2, hv[2], lv[2]); split2(o3, hv[3], lv[3]);
    // split layout: hi at byte g*32 + 2j, lo at +16 ; our 4 ch are j0=ch0&7 in {0,4}
    unsigned short* o = h2 + (size_t)node * (2 * HC) + ((ch0 >> 3) * 16) + (ch0 & 7);
    *reinterpret_cast<uint2*>(o)     = *reinterpret_cast<uint2*>(hv);
    *reinterpret_cast<uint2*>(o + 8) = *reinterpret_cast<uint2*>(lv);
}

// ---------------------------------------------------------------------------
// Pool stage 1: per (graph, quarter) partial sums (deterministic, no atomics)
// ---------------------------------------------------------------------------
__global__ __launch_bounds__(256) void pool_part_kernel(const unsigned short* __restrict__ h2,
                                                        const int* __restrict__ batch,
                                                        float* __restrict__ partial) {
    const int g = blockIdx.x, part = blockIdx.y;
    int lo = 0, hi = NODES;
    while (lo < hi) { int mid = (lo + hi) >> 1; if (batch[mid] < g) lo = mid + 1; else hi = mid; }
    const int s = lo;
    lo = s; hi = NODES;
    while (lo < hi) { int mid = (lo + hi) >> 1; if (batch[mid] < g + 1) lo = mid + 1; else hi = mid; }
    const int e = lo, cnt = e - s;
    const int ps = s + (cnt * part) / 4;
    const int pe = s + (cnt * (part + 1)) / 4;

    const int c0 = threadIdx.x * 2;
    const int boff = ((c0 >> 3) * 16) + (c0 & 7);
    float s0 = 0.f, s1 = 0.f;
    for (int r = ps; r < pe; ++r) {
        const unsigned short* p = h2 + (size_t)r * (2 * HC) + boff;
        s0 += bf16f(p[0]) + bf16f(p[8]);
        s1 += bf16f(p[1]) + bf16f(p[9]);
    }
    float* o = partial + ((size_t)(g * 4 + part)) * HC;
    o[c0] = s0; o[c0 + 1] = s1;
}

// ---------------------------------------------------------------------------
// Pool stage 2 + classifier
// ---------------------------------------------------------------------------
__global__ __launch_bounds__(256) void cls_kernel(const float* __restrict__ partial,
                                                  const int* __restrict__ batch,
                                                  const float* __restrict__ W,
                                                  const float* __restrict__ cb,
                                                  float* __restrict__ outp) {
    const int g = blockIdx.x;
    __shared__ float pooled[HC];
    int lo = 0, hi = NODES;
    while (lo < hi) { int mid = (lo + hi) >> 1; if (batch[mid] < g) lo = mid + 1; else hi = mid; }
    const int s = lo;
    lo = s; hi = NODES;
    while (lo < hi) { int mid = (lo + hi) >> 1; if (batch[mid] < g + 1) lo = mid + 1; else hi = mid; }
    const int cnt = lo - s;

    const int c0 = threadIdx.x * 2;
    float s0 = 0.f, s1 = 0.f;
    #pragma unroll
    for (int part = 0; part < 4; ++part) {
        const float* p = partial + ((size_t)(g * 4 + part)) * HC;
        s0 += p[c0]; s1 += p[c0 + 1];
    }
    const float invc = cnt > 0 ? 1.f / (float)cnt : 0.f;
    pooled[c0] = s0 * invc; pooled[c0 + 1] = s1 * invc;
    __syncthreads();

    const int lane = threadIdx.x & 63, wid = threadIdx.x >> 6;
    for (int o = wid; o < OUT_F; o += 4) {
        float p = 0.f;
        for (int c = lane; c < HC; c += 64) p += pooled[c] * W[c * OUT_F + o];
        #pragma unroll
        for (int off2 = 32; off2; off2 >>= 1) p += __shfl_xor(p, off2);
        if (lane == 0) outp[g * OUT_F + o] = p + cb[o];
    }
}

// ---------------------------------------------------------------------------
// Host-side launch
// ---------------------------------------------------------------------------
extern "C" void kernel_launch(void* const* d_in, const int* in_sizes, int n_in,
                              void* d_out, int out_size, void* d_ws, size_t ws_size,
                              hipStream_t stream) {
    const float* x      = (const float*)d_in[0];
    const int*   ei     = (const int*)d_in[1];
    const int*   batch  = (const int*)d_in[2];
    const float* pre_W  = (const float*)d_in[3];
    const float* pre_b  = (const float*)d_in[4];
    const float* cls_W  = (const float*)d_in[5];
    const float* cls_b  = (const float*)d_in[6];
    const float* Wl[3]; const float* bl[3]; const float* Wr[3];
    const float* br[3]; const float* attw[3]; const float* bw[3];
    for (int l = 0; l < 3; ++l) {
        Wl[l]   = (const float*)d_in[7 + 6 * l + 0];
        bl[l]   = (const float*)d_in[7 + 6 * l + 1];
        Wr[l]   = (const float*)d_in[7 + 6 * l + 2];
        br[l]   = (const float*)d_in[7 + 6 * l + 3];
        attw[l] = (const float*)d_in[7 + 6 * l + 4];
        bw[l]   = (const float*)d_in[7 + 6 * l + 5];
    }
    float* outp = (float*)d_out;

    // ---- workspace carve (~128 MB, lifetime-aliased) ----
    char* ws = (char*)d_ws;
    size_t off = 0;
    auto alloc = [&](size_t b) { char* p = ws + off; off += (b + 255) & ~(size_t)255; return p; };
    float* xlr = (float*)alloc((size_t)MPAD * XLRW * 4);                // 82.3 MB
    unsigned short* h2 = (unsigned short*)alloc((size_t)MPAD * 2 * HC * 2); // 41.2 MB
    unsigned short* WT2f = (unsigned short*)alloc((size_t)1024 * 2 * HC * 2); // 2.1 MB (K<=512)
    unsigned short* preWT2 = (unsigned short*)alloc((size_t)HID * 2 * IN_F * 2); // 131 KB
    float* biascat = (float*)alloc(3 * 1024 * 4);
    int* counts  = (int*)alloc(NODES * 4);
    int* offsets = (int*)alloc((NODES + 1) * 4);
    int* cursor  = (int*)alloc(NODES * 4);
    int* srcsb   = (int*)alloc((size_t)EPRIME * 4);
    // aliases (disjoint lifetimes):
    unsigned short* x2 = (unsigned short*)xlr;   // dead before xlr written (L1 GEMM)
    float* partial = xlr;                        // pool runs after xlr is dead

    // ---- edge sort ----
    hipMemsetAsync(counts, 0, NODES * 4, stream);
    hist_kernel<<<(EPRIME + 255) / 256, 256, 0, stream>>>(ei, counts);
    scan_kernel<<<1, 1024, 0, stream>>>(counts, offsets, cursor);
    scatter_kernel<<<(EPRIME + 255) / 256, 256, 0, stream>>>(ei, cursor, srcsb);

    // ---- conversions ----
    convert_x_kernel<<<(MPAD * (IN_F / 8) + 255) / 256, 256, 0, stream>>>(x, x2);
    convert_w_kernel<<<(HID * (IN_F / 8) + 255) / 256, 256, 0, stream>>>(pre_W, preWT2, IN_F, HID, 5);
    build_bias_kernel<<<12, 256, 0, stream>>>(bl[0], br[0], bl[1], br[1], bl[2], br[2], biascat);
    // layer 0 fused weights: rows 0..511 = Wl, rows 512..1023 = Wr (row stride 2*K shorts)
    convert_w_kernel<<<(HC * (HID / 8) + 255) / 256, 256, 0, stream>>>(Wl[0], WT2f, HID, HC, 4);
    convert_w_kernel<<<(HC * (HID / 8) + 255) / 256, 256, 0, stream>>>(Wr[0], WT2f + (size_t)512 * 2 * HID, HID, HC, 4);

    // ---- pre layer: h = elu(x @ pre_W + pre_b), split-written ----
    mfma_gemm_kernel<1, 1><<<dim3(157, 1), 256, 0, stream>>>(x2, preWT2, pre_b,
                                                             nullptr, h2, NODES, HID, IN_F);

    // ---- layer 1 (fused Wl|Wr GEMM, N=1024) ----
    mfma_gemm_kernel<0, 0><<<dim3(157, 8), 256, 0, stream>>>(h2, WT2f, biascat, xlr, nullptr, NODES, 1024, HID);
    convert_w_kernel<<<(HC * (HC / 8) + 255) / 256, 256, 0, stream>>>(Wl[1], WT2f, HC, HC, 6);
    convert_w_kernel<<<(HC * (HC / 8) + 255) / 256, 256, 0, stream>>>(Wr[1], WT2f + (size_t)512 * 2 * HC, HC, HC, 6);
    gat_edge_kernel<<<MPAD / 2, 256, 0, stream>>>(xlr, attw[0], bw[0], offsets, srcsb, h2);

    // ---- layer 2 ----
    mfma_gemm_kernel<0, 0><<<dim3(157, 8), 256, 0, stream>>>(h2, WT2f, biascat + 1024, xlr, nullptr, NODES, 1024, HC);
    convert_w_kernel<<<(HC * (HC / 8) + 255) / 256, 256, 0, stream>>>(Wl[2], WT2f, HC, HC, 6);
    convert_w_kernel<<<(HC * (HC / 8) + 255) / 256, 256, 0, stream>>>(Wr[2], WT2f + (size_t)512 * 2 * HC, HC, HC, 6);
    gat_edge_kernel<<<MPAD / 2, 256, 0, stream>>>(xlr, attw[1], bw[1], offsets, srcsb, h2);

    // ---- layer 3 ----
    mfma_gemm_kernel<0, 0><<<dim3(157, 8), 256, 0, stream>>>(h2, WT2f, biascat + 2048, xlr, nullptr, NODES, 1024, HC);
    gat_edge_kernel<<<MPAD / 2, 256, 0, stream>>>(xlr, attw[2], bw[2], offsets, srcsb, h2);

    // ---- pool + classifier ----
    pool_part_kernel<<<dim3(NGRAPH, 4), 256, 0, stream>>>(h2, batch, partial);
    cls_kernel<<<NGRAPH, 256, 0, stream>>>(partial, batch, cls_W, cls_b, outp);
}